// Round 4
// baseline (275.270 us; speedup 1.0000x reference)
//
#include <hip/hip_runtime.h>

// WaveletLayer fused v4: 4 stages, 3 barriers.
//  - s1: x*diag_b global->regs, computes a1 -> A1 (LDS), d1 -> Cc d1 region.
//  - s23: composite 10-tap stride-4 filters (G=lo*lo, H=hi*lo cascade) give
//    a3,d3 directly from a1; d2 (4-tap stride-2) shares the same window.
//    One stage, one barrier, no A2 buffer.
//  - gather: cp[0:2563) = c[perm]*g -> P (only live prefix; perm/g/s
//    prefetched into registers at kernel start).
//  - r123: thread u recomputes r1[2u..2u+3] from cp (6 linear LDS reads),
//    builds r2[4u..4u+4] in regs, writes both output quads * diag_s.
//    No R1 buffer, no barrier after.
// LDS = 2568+4112 floats = 26.7 KB -> 4 blocks/CU x 8 waves = 32 waves/CU.
//
// Cc layout: a3[0:514) d3[514:1028) d2[1028:2054) gap[2054:2056) d1@2056+[0:2049)
//            (gather translation: j >= 2054 ? j+2 : j)
// rawA: a1[-6..2056) at rawA+8 (A1); then P = cp[0:2563) at rawA+0 (a1 dead).

#define NT 512

__global__ __launch_bounds__(NT, 8) void wavelet_fused(
    const float* __restrict__ x,
    const float* __restrict__ diag_b,
    const float* __restrict__ diag_g,
    const float* __restrict__ diag_s,
    const float* __restrict__ dec_lo,
    const float* __restrict__ dec_hi,
    const float* __restrict__ rec_lo,
    const float* __restrict__ rec_hi,
    const int*   __restrict__ perm_idx,
    float* __restrict__ out)
{
    __shared__ __align__(16) float rawA[2568];
    __shared__ __align__(16) float rawC[4112];
    float* const A1 = rawA + 8;     // a1[i], i in [-6, 2056)
    float* const P  = rawA;         // cp[0:2563) after decomposition
    float* const Cc = rawC;

    const int tid = threadIdx.x;
    const long row = blockIdx.x;

    // ---- prefetch row-invariant tables into registers (hide under s1-s23) ----
    int4   pq0 = ((const int4*)perm_idx)[tid];          // perm[4t .. 4t+4)
    float4 gq0 = ((const float4*)diag_g)[tid];
    int4   pq1; float4 gq1;
    if (tid < 128) {                                     // perm[2048 .. 2560)
        pq1 = ((const int4*)perm_idx)[512 + tid];
        gq1 = ((const float4*)diag_g)[512 + tid];
    }
    int pt = 0; float gt = 0.0f;
    if (tid < 3) { pt = perm_idx[2560 + tid]; gt = diag_g[2560 + tid]; }
    float4 sv0 = ((const float4*)diag_s)[2*tid];
    float4 sv1 = ((const float4*)diag_s)[2*tid + 1];

    const float lo0=dec_lo[0], lo1=dec_lo[1], lo2=dec_lo[2], lo3=dec_lo[3];
    const float hi0=dec_hi[0], hi1=dec_hi[1], hi2=dec_hi[2], hi3=dec_hi[3];
    const float rl0=rec_lo[0], rl1=rec_lo[1], rl2=rec_lo[2], rl3=rec_lo[3];
    const float rh0=rec_hi[0], rh1=rec_hi[1], rh2=rec_hi[2], rh3=rec_hi[3];

    // zero pads: a1[-6..0) and a1[2049..2056)
    if (tid < 6) rawA[2 + tid] = 0.0f;
    if (tid < 7) A1[2049 + tid] = 0.0f;

    // ---- s1: global regs -> a1 (A1), d1 (Cc+2056) ----
    {
        const float* xr = x + row * 4096;
        float4 xv0 = *(const float4*)(xr + 8*tid);
        float4 xv1 = *(const float4*)(xr + 8*tid + 4);
        float4 bv0 = *(const float4*)(diag_b + 8*tid);
        float4 bv1 = *(const float4*)(diag_b + 8*tid + 4);
        float vm2 = 0.0f, vm1 = 0.0f;
        if (tid > 0) {
            float2 xm = *(const float2*)(xr + 8*tid - 2);
            float2 bm = *(const float2*)(diag_b + 8*tid - 2);
            vm2 = xm.x * bm.x; vm1 = xm.y * bm.y;
        }
        float v0 = xv0.x*bv0.x, v1 = xv0.y*bv0.y, v2 = xv0.z*bv0.z, v3 = xv0.w*bv0.w;
        float v4 = xv1.x*bv1.x, v5 = xv1.y*bv1.y, v6 = xv1.z*bv1.z, v7 = xv1.w*bv1.w;
        float4 av, dv;
        av.x = lo0*v1 + lo1*v0 + lo2*vm1 + lo3*vm2;
        dv.x = hi0*v1 + hi1*v0 + hi2*vm1 + hi3*vm2;
        av.y = lo0*v3 + lo1*v2 + lo2*v1 + lo3*v0;
        dv.y = hi0*v3 + hi1*v2 + hi2*v1 + hi3*v0;
        av.z = lo0*v5 + lo1*v4 + lo2*v3 + lo3*v2;
        dv.z = hi0*v5 + hi1*v4 + hi2*v3 + hi3*v2;
        av.w = lo0*v7 + lo1*v6 + lo2*v5 + lo3*v4;
        dv.w = hi0*v7 + hi1*v6 + hi2*v5 + hi3*v4;
        *(float4*)(A1 + 4*tid) = av;
        *(float4*)(Cc + 2056 + 4*tid) = dv;
        if (tid == 0) {
            float xa = xr[4094]*diag_b[4094], xb = xr[4095]*diag_b[4095];
            A1[2048]        = lo2*xb + lo3*xa;
            Cc[2056 + 2048] = hi2*xb + hi3*xa;
        }
    }

    // composite cascade filters (wave-uniform; fills barrier wait)
    float loA[4] = {lo0, lo1, lo2, lo3};
    float hiA[4] = {hi0, hi1, hi2, hi3};
    float G[10], H[10];
    #pragma unroll
    for (int k = 0; k < 10; ++k) { G[k] = 0.0f; H[k] = 0.0f; }
    #pragma unroll
    for (int s = 0; s < 4; ++s)
        #pragma unroll
        for (int t = 0; t < 4; ++t) {
            G[2*s + t] += loA[s] * loA[t];
            H[2*s + t] += hiA[s] * loA[t];
        }
    __syncthreads();

    // ---- s23: a1 -> a3[p], d3[p], d2[2p..2p+2) ; window a1[4p-6..4p+4) ----
    {
        const int p = tid;
        float W[10];
        float2 w0 = *(const float2*)(A1 + 4*p - 6);
        float4 w1 = *(const float4*)(A1 + 4*p - 4);
        float4 w2 = *(const float4*)(A1 + 4*p);
        W[0]=w0.x; W[1]=w0.y; W[2]=w1.x; W[3]=w1.y; W[4]=w1.z; W[5]=w1.w;
        W[6]=w2.x; W[7]=w2.y; W[8]=w2.z; W[9]=w2.w;
        float a3v = 0.0f, d3v = 0.0f;
        #pragma unroll
        for (int j = 0; j < 10; ++j) { a3v += G[9-j]*W[j]; d3v += H[9-j]*W[j]; }
        Cc[p]       = a3v;
        Cc[514 + p] = d3v;
        // d2[2p]: taps a1[4p-2..4p+2) = W[4..8); d2[2p+1]: W[6..10)
        float2 dd;
        dd.x = hi0*W[7] + hi1*W[6] + hi2*W[5] + hi3*W[4];
        dd.y = hi0*W[9] + hi1*W[8] + hi2*W[7] + hi3*W[6];
        *(float2*)(Cc + 1028 + 2*p) = dd;
        if (p < 2) {  // tails: a3/d3[512+p], d2[1024+p]
            int n = 512 + p;
            float acc = 0.0f, dcc = 0.0f;
            #pragma unroll
            for (int k = 0; k < 10; ++k) {
                float av = A1[4*n + 3 - k];
                acc += G[k]*av; dcc += H[k]*av;
            }
            Cc[n] = acc; Cc[514 + n] = dcc;
            int m = 1024 + p;
            Cc[1028 + m] = hi0*A1[2*m+1] + hi1*A1[2*m] + hi2*A1[2*m-1] + hi3*A1[2*m-2];
        }
    }
    __syncthreads();

    // ---- gather: cp[i] = c[perm[i]]*g[i], i in [0:2563) -> P ----
    {
        float4 cv;
        cv.x = Cc[pq0.x + (pq0.x >= 2054 ? 2 : 0)] * gq0.x;
        cv.y = Cc[pq0.y + (pq0.y >= 2054 ? 2 : 0)] * gq0.y;
        cv.z = Cc[pq0.z + (pq0.z >= 2054 ? 2 : 0)] * gq0.z;
        cv.w = Cc[pq0.w + (pq0.w >= 2054 ? 2 : 0)] * gq0.w;
        *(float4*)(P + 4*tid) = cv;                        // [0:2048)
        if (tid < 128) {
            float4 cw;
            cw.x = Cc[pq1.x + (pq1.x >= 2054 ? 2 : 0)] * gq1.x;
            cw.y = Cc[pq1.y + (pq1.y >= 2054 ? 2 : 0)] * gq1.y;
            cw.z = Cc[pq1.z + (pq1.z >= 2054 ? 2 : 0)] * gq1.z;
            cw.w = Cc[pq1.w + (pq1.w >= 2054 ? 2 : 0)] * gq1.w;
            *(float4*)(P + 2048 + 4*tid) = cw;             // [2048:2560)
        }
        if (tid < 3) P[2560 + tid] = Cc[pt + (pt >= 2054 ? 2 : 0)] * gt;
    }
    __syncthreads();

    // ---- r123: recompute r1[2u..2u+3], build r2[4u..4u+4], write out ----
    {
        const int u = tid;
        // r1 from cp a-band [u..u+2] and d'-band [2049+u..2051+u]
        float a0 = P[u], a1v = P[u + 1], a2v = P[u + 2];
        float b0 = P[2049 + u], b1 = P[2050 + u], b2 = P[2051 + u];
        float r10 = rl2*a0  + rl0*a1v + rh2*b0 + rh0*b1;   // r1[2u]
        float r11 = rl3*a0  + rl1*a1v + rh3*b0 + rh1*b1;   // r1[2u+1]
        float r12 = rl2*a1v + rl0*a2v + rh2*b1 + rh0*b2;   // r1[2u+2]
        float r13 = rl3*a1v + rl1*a2v + rh3*b1 + rh1*b2;   // r1[2u+3]
        float2 ea = *(const float2*)(P + 1026 + 2*u);      // D[2u],D[2u+1]
        float2 eb = *(const float2*)(P + 1028 + 2*u);      // D[2u+2],D[2u+3]
        float s0  = rl2*r10 + rl0*r11 + rh2*ea.x + rh0*ea.y;
        float s1v = rl3*r10 + rl1*r11 + rh3*ea.x + rh1*ea.y;
        float s2v = rl2*r11 + rl0*r12 + rh2*ea.y + rh0*eb.x;
        float s3v = rl3*r11 + rl1*r12 + rh3*ea.y + rh1*eb.x;
        float s4  = rl2*r12 + rl0*r13 + rh2*eb.x + rh0*eb.y;
        float2 fa = *(const float2*)(P + 514 + 4*u);       // cp[514+4u..]
        float2 fb = *(const float2*)(P + 516 + 4*u);
        float  f4 = P[518 + 4*u];
        float f0 = fa.x, f1 = fa.y, f2 = fb.x, f3 = fb.y;
        float4 o0, o1;
        o0.x = (rl2*s0  + rl0*s1v + rh2*f0 + rh0*f1) * sv0.x;
        o0.y = (rl3*s0  + rl1*s1v + rh3*f0 + rh1*f1) * sv0.y;
        o0.z = (rl2*s1v + rl0*s2v + rh2*f1 + rh0*f2) * sv0.z;
        o0.w = (rl3*s1v + rl1*s2v + rh3*f1 + rh1*f2) * sv0.w;
        o1.x = (rl2*s2v + rl0*s3v + rh2*f2 + rh0*f3) * sv1.x;
        o1.y = (rl3*s2v + rl1*s3v + rh3*f2 + rh1*f3) * sv1.y;
        o1.z = (rl2*s3v + rl0*s4  + rh2*f3 + rh0*f4) * sv1.z;
        o1.w = (rl3*s3v + rl1*s4  + rh3*f3 + rh1*f4) * sv1.w;
        float4* outr = (float4*)(out + row * 4096);
        outr[2*u]     = o0;
        outr[2*u + 1] = o1;
    }
}

extern "C" void kernel_launch(void* const* d_in, const int* in_sizes, int n_in,
                              void* d_out, int out_size, void* d_ws, size_t ws_size,
                              hipStream_t stream) {
    const float* x       = (const float*)d_in[0];
    const float* diag_b  = (const float*)d_in[1];
    const float* diag_g  = (const float*)d_in[2];
    const float* diag_s  = (const float*)d_in[3];
    const float* dec_lo  = (const float*)d_in[4];
    const float* dec_hi  = (const float*)d_in[5];
    const float* rec_lo  = (const float*)d_in[6];
    const float* rec_hi  = (const float*)d_in[7];
    const int*   perm    = (const int*)d_in[8];
    float* out = (float*)d_out;

    const int B = in_sizes[0] / 4096;  // 8192 rows
    wavelet_fused<<<B, NT, 0, stream>>>(
        x, diag_b, diag_g, diag_s, dec_lo, dec_hi, rec_lo, rec_hi, perm, out);
}

// Round 6
// 265.005 us; speedup vs baseline: 1.0387x; 1.0387x over previous
//
#include <hip/hip_runtime.h>

// WaveletLayer fused v5: multi-row software-pipelined blocks.
//  - Each block processes ROWS=4 consecutive rows. While row r runs its
//    LDS/VALU stages, row r+1's x-loads are already in flight (issued right
//    after row r's s1 consumes its registers). Breaks the phase-aligned
//    burstiness that left HBM at 27% / VALU at 19% / LDS all idling.
//  - diag_b register-hoisted once per block; s1 tail computed by lane 511
//    from its own registers (no global reload).
//  - Stages per row: s1 | s2 | s3 | gather | r123 (r1 recomputed in regs,
//    fused with r2+r3 -> direct coalesced store). No spill-prone arrays.
//  - LDS = 3088+4112 floats = 28.8 KB -> 4 blocks/CU x 8 waves = 32 w/CU.
//
// Cc layout: a3[0:514) d3[514:1028) d2[1028:2054) gap[2054:2056) d1@2056+[0:2049)
//            (gather translation: j >= 2054 ? j+2 : j)
// rawA: A1 = a1[-2..2052) @rawA+4, A2 = a2[-2..1028) @rawA+2060;
//       P  = cp[0:2563) @rawA+0 (gather clobbers a1/a2 pads -> re-zeroed per row).

#define NT   512
#define ROWS 4

__global__ __launch_bounds__(NT, 8) void wavelet_fused(
    const float* __restrict__ x,
    const float* __restrict__ diag_b,
    const float* __restrict__ diag_g,
    const float* __restrict__ diag_s,
    const float* __restrict__ dec_lo,
    const float* __restrict__ dec_hi,
    const float* __restrict__ rec_lo,
    const float* __restrict__ rec_hi,
    const int*   __restrict__ perm_idx,
    float* __restrict__ out)
{
    __shared__ __align__(16) float rawA[3088];
    __shared__ __align__(16) float rawC[4112];
    float* const A1 = rawA + 4;     // a1[i], i in [-2, 2052)
    float* const A2 = rawA + 2060;  // a2[i], i in [-2, 1028)
    float* const P  = rawA;         // cp[0:2563) during inverse
    float* const Cc = rawC;

    const int tid = threadIdx.x;
    const long row0 = (long)blockIdx.x * ROWS;

    const float lo0=dec_lo[0], lo1=dec_lo[1], lo2=dec_lo[2], lo3=dec_lo[3];
    const float hi0=dec_hi[0], hi1=dec_hi[1], hi2=dec_hi[2], hi3=dec_hi[3];
    const float rl0=rec_lo[0], rl1=rec_lo[1], rl2=rec_lo[2], rl3=rec_lo[3];
    const float rh0=rec_hi[0], rh1=rec_hi[1], rh2=rec_hi[2], rh3=rec_hi[3];

    // diag_b register-hoisted (row-invariant)
    float4 bv0 = *(const float4*)(diag_b + 8*tid);
    float4 bv1 = *(const float4*)(diag_b + 8*tid + 4);
    float2 bm; bm.x = 0.0f; bm.y = 0.0f;
    if (tid > 0) bm = *(const float2*)(diag_b + 8*tid - 2);

    // once-per-block pad: a2[1026,1027] (never clobbered by P, max idx 2562)
    if (tid < 2) rawA[3086 + tid] = 0.0f;

#define LOADX(ROW, XV0, XV1, XM) do {                                   \
        const float* xr_ = x + (long)(ROW) * 4096;                      \
        XV0 = *(const float4*)(xr_ + 8*tid);                            \
        XV1 = *(const float4*)(xr_ + 8*tid + 4);                        \
        XM.x = 0.0f; XM.y = 0.0f;                                       \
        if (tid > 0) XM = *(const float2*)(xr_ + 8*tid - 2);            \
    } while (0)

#define ROW_BODY(ROW, XV0, XV1, XM, PF) {                               \
    /* per-row pads (P clobbered them): a1[-2:0), a1[2049:2052), a2[-2:0) */ \
    if (tid < 2) rawA[2 + tid]    = 0.0f;                               \
    if (tid < 3) rawA[2053 + tid] = 0.0f;                               \
    if (tid < 2) rawA[2058 + tid] = 0.0f;                               \
    /* ---- s1: x*diag_b (regs) -> a1 (A1), d1 (Cc+2056) ---- */        \
    {                                                                   \
        float v0 = XV0.x*bv0.x, v1 = XV0.y*bv0.y,                       \
              v2 = XV0.z*bv0.z, v3 = XV0.w*bv0.w;                       \
        float v4 = XV1.x*bv1.x, v5 = XV1.y*bv1.y,                       \
              v6 = XV1.z*bv1.z, v7 = XV1.w*bv1.w;                       \
        float vm2 = XM.x*bm.x, vm1 = XM.y*bm.y;                         \
        float4 av, dv;                                                  \
        av.x = lo0*v1 + lo1*v0 + lo2*vm1 + lo3*vm2;                     \
        dv.x = hi0*v1 + hi1*v0 + hi2*vm1 + hi3*vm2;                     \
        av.y = lo0*v3 + lo1*v2 + lo2*v1 + lo3*v0;                       \
        dv.y = hi0*v3 + hi1*v2 + hi2*v1 + hi3*v0;                       \
        av.z = lo0*v5 + lo1*v4 + lo2*v3 + lo3*v2;                       \
        dv.z = hi0*v5 + hi1*v4 + hi2*v3 + hi3*v2;                       \
        av.w = lo0*v7 + lo1*v6 + lo2*v5 + lo3*v4;                       \
        dv.w = hi0*v7 + hi1*v6 + hi2*v5 + hi3*v4;                       \
        *(float4*)(A1 + 4*tid) = av;                                    \
        *(float4*)(Cc + 2056 + 4*tid) = dv;                             \
        if (tid == 511) {  /* tail n=2048 from lane 511's own regs */   \
            A1[2048]        = lo2*v7 + lo3*v6;                          \
            Cc[2056 + 2048] = hi2*v7 + hi3*v6;                          \
        }                                                               \
    }                                                                   \
    PF;  /* issue next row's x loads; resolve ~4 stages later */        \
    __syncthreads();                                                    \
    /* ---- s2: a1 -> a2 (A2), d2 (Cc+1028) ---- */                     \
    for (int p = tid; p < 513; p += NT) {                               \
        float2 u0 = *(const float2*)(A1 + 4*p - 2);                     \
        float4 u1 = *(const float4*)(A1 + 4*p);                         \
        float2 ap, dp;                                                  \
        ap.x = lo0*u1.y + lo1*u1.x + lo2*u0.y + lo3*u0.x;               \
        dp.x = hi0*u1.y + hi1*u1.x + hi2*u0.y + hi3*u0.x;               \
        ap.y = lo0*u1.w + lo1*u1.z + lo2*u1.y + lo3*u1.x;               \
        dp.y = hi0*u1.w + hi1*u1.z + hi2*u1.y + hi3*u1.x;               \
        *(float2*)(A2 + 2*p)        = ap;                               \
        *(float2*)(Cc + 1028 + 2*p) = dp;                               \
    }                                                                   \
    __syncthreads();                                                    \
    /* ---- s3: a2 -> a3 (Cc[0:514)), d3 (Cc[514:1028)) ---- */         \
    for (int p = tid; p < 257; p += NT) {                               \
        float2 u0 = *(const float2*)(A2 + 4*p - 2);                     \
        float4 u1 = *(const float4*)(A2 + 4*p);                         \
        float2 ap, dp;                                                  \
        ap.x = lo0*u1.y + lo1*u1.x + lo2*u0.y + lo3*u0.x;               \
        dp.x = hi0*u1.y + hi1*u1.x + hi2*u0.y + hi3*u0.x;               \
        ap.y = lo0*u1.w + lo1*u1.z + lo2*u1.y + lo3*u1.x;               \
        dp.y = hi0*u1.w + hi1*u1.z + hi2*u1.y + hi3*u1.x;               \
        *(float2*)(Cc + 2*p)       = ap;                                \
        *(float2*)(Cc + 514 + 2*p) = dp;                                \
    }                                                                   \
    __syncthreads();                                                    \
    /* ---- gather: cp[i] = c[perm[i]]*g[i], i in [0:2563) -> P ---- */ \
    {                                                                   \
        int4   pj = ((const int4*)perm_idx)[tid];                       \
        float4 g4 = ((const float4*)diag_g)[tid];                       \
        float4 cv;                                                      \
        cv.x = Cc[pj.x + (pj.x >= 2054 ? 2 : 0)] * g4.x;                \
        cv.y = Cc[pj.y + (pj.y >= 2054 ? 2 : 0)] * g4.y;                \
        cv.z = Cc[pj.z + (pj.z >= 2054 ? 2 : 0)] * g4.z;                \
        cv.w = Cc[pj.w + (pj.w >= 2054 ? 2 : 0)] * g4.w;                \
        *(float4*)(P + 4*tid) = cv;                                     \
        if (tid < 128) {                                                \
            int4   pk = ((const int4*)perm_idx)[512 + tid];             \
            float4 gk = ((const float4*)diag_g)[512 + tid];             \
            float4 cw;                                                  \
            cw.x = Cc[pk.x + (pk.x >= 2054 ? 2 : 0)] * gk.x;            \
            cw.y = Cc[pk.y + (pk.y >= 2054 ? 2 : 0)] * gk.y;            \
            cw.z = Cc[pk.z + (pk.z >= 2054 ? 2 : 0)] * gk.z;            \
            cw.w = Cc[pk.w + (pk.w >= 2054 ? 2 : 0)] * gk.w;            \
            *(float4*)(P + 2048 + 4*tid) = cw;                          \
        }                                                               \
        if (tid < 3) {                                                  \
            int pt = perm_idx[2560 + tid];                              \
            P[2560 + tid] = Cc[pt + (pt >= 2054 ? 2 : 0)] * diag_g[2560 + tid]; \
        }                                                               \
    }                                                                   \
    __syncthreads();                                                    \
    /* ---- r123: recompute r1[2u..2u+3], r2[4u..4u+4] in regs, store ---- */ \
    {                                                                   \
        const int u = tid;                                              \
        float a0 = P[u], a1v = P[u + 1], a2v = P[u + 2];                \
        float b0 = P[2049 + u], b1 = P[2050 + u], b2 = P[2051 + u];     \
        float r10 = rl2*a0  + rl0*a1v + rh2*b0 + rh0*b1;                \
        float r11 = rl3*a0  + rl1*a1v + rh3*b0 + rh1*b1;                \
        float r12 = rl2*a1v + rl0*a2v + rh2*b1 + rh0*b2;                \
        float r13 = rl3*a1v + rl1*a2v + rh3*b1 + rh1*b2;                \
        float2 ea = *(const float2*)(P + 1026 + 2*u);                   \
        float2 eb = *(const float2*)(P + 1028 + 2*u);                   \
        float s0  = rl2*r10 + rl0*r11 + rh2*ea.x + rh0*ea.y;            \
        float s1v = rl3*r10 + rl1*r11 + rh3*ea.x + rh1*ea.y;            \
        float s2v = rl2*r11 + rl0*r12 + rh2*ea.y + rh0*eb.x;            \
        float s3v = rl3*r11 + rl1*r12 + rh3*ea.y + rh1*eb.x;            \
        float s4  = rl2*r12 + rl0*r13 + rh2*eb.x + rh0*eb.y;            \
        float2 fa = *(const float2*)(P + 514 + 4*u);                    \
        float2 fb = *(const float2*)(P + 516 + 4*u);                    \
        float  f4 = P[518 + 4*u];                                       \
        float4 sv0 = ((const float4*)diag_s)[2*u];                      \
        float4 sv1 = ((const float4*)diag_s)[2*u + 1];                  \
        float4 o0, o1;                                                  \
        o0.x = (rl2*s0  + rl0*s1v + rh2*fa.x + rh0*fa.y) * sv0.x;       \
        o0.y = (rl3*s0  + rl1*s1v + rh3*fa.x + rh1*fa.y) * sv0.y;       \
        o0.z = (rl2*s1v + rl0*s2v + rh2*fa.y + rh0*fb.x) * sv0.z;       \
        o0.w = (rl3*s1v + rl1*s2v + rh3*fa.y + rh1*fb.x) * sv0.w;       \
        o1.x = (rl2*s2v + rl0*s3v + rh2*fb.x + rh0*fb.y) * sv1.x;       \
        o1.y = (rl3*s2v + rl1*s3v + rh3*fb.x + rh1*fb.y) * sv1.y;       \
        o1.z = (rl2*s3v + rl0*s4  + rh2*fb.y + rh0*f4  ) * sv1.z;       \
        o1.w = (rl3*s3v + rl1*s4  + rh3*fb.y + rh1*f4  ) * sv1.w;       \
        float4* outr = (float4*)(out + (long)(ROW) * 4096);             \
        outr[2*u]     = o0;                                             \
        outr[2*u + 1] = o1;                                             \
    }                                                                   \
}

    float4 xA0, xA1; float2 xAm;
    float4 xB0, xB1; float2 xBm;
    LOADX(row0, xA0, xA1, xAm);

    ROW_BODY(row0 + 0, xA0, xA1, xAm, LOADX(row0 + 1, xB0, xB1, xBm));
    __syncthreads();
    ROW_BODY(row0 + 1, xB0, xB1, xBm, LOADX(row0 + 2, xA0, xA1, xAm));
    __syncthreads();
    ROW_BODY(row0 + 2, xA0, xA1, xAm, LOADX(row0 + 3, xB0, xB1, xBm));
    __syncthreads();
    ROW_BODY(row0 + 3, xB0, xB1, xBm, ((void)0));

#undef ROW_BODY
#undef LOADX
}

extern "C" void kernel_launch(void* const* d_in, const int* in_sizes, int n_in,
                              void* d_out, int out_size, void* d_ws, size_t ws_size,
                              hipStream_t stream) {
    const float* x       = (const float*)d_in[0];
    const float* diag_b  = (const float*)d_in[1];
    const float* diag_g  = (const float*)d_in[2];
    const float* diag_s  = (const float*)d_in[3];
    const float* dec_lo  = (const float*)d_in[4];
    const float* dec_hi  = (const float*)d_in[5];
    const float* rec_lo  = (const float*)d_in[6];
    const float* rec_hi  = (const float*)d_in[7];
    const int*   perm    = (const int*)d_in[8];
    float* out = (float*)d_out;

    const int B = in_sizes[0] / 4096;   // 8192 rows
    wavelet_fused<<<B / ROWS, NT, 0, stream>>>(
        x, diag_b, diag_g, diag_s, dec_lo, dec_hi, rec_lo, rec_hi, perm, out);
}